// Round 4
// baseline (293.285 us; speedup 1.0000x reference)
//
#include <hip/hip_runtime.h>

// Per-pixel predicted 3x3 filtering, fp32:
// out[b,c,h,w] = sum_{f,ki,kj} k[b, f*9+ki*3+kj, h, w] * x[b, f*64+c, h+ki-1, w+kj-1]
//              + k[b, 18, h, w] * skip[b,c,h,w]
// B=4, C=64, NF=2, H=W=256. Min HBM traffic ~288 MB -> ~46 us floor @ 6.3 TB/s.
//
// R4: latency-bound fix. Each wave = full 256-px row (4 px/lane), owns 2
// channels, and issues ALL 14 float4 global loads into registers UP FRONT
// (explicit arrays force liveness -> compiler must batch loads, ~14 KB
// outstanding per wave). k staging + barrier overlap the x-load latency.
// grid = (b, h, cg=8); __launch_bounds__(256,4) pins 4 waves/SIMD.

constexpr int Hh = 256;
constexpr int Ww = 256;
constexpr int HW = Hh * Ww;
constexpr int C  = 64;
constexpr int NF = 2;
constexpr int KS = 19;

__global__ __launch_bounds__(256, 4) void filt_kernel(
    const float* __restrict__ kk,
    const float* __restrict__ x,
    const float* __restrict__ skip,
    float* __restrict__ out) {
  const int blk  = blockIdx.x;       // ((b*256 + h) << 3) | cg
  const int cg   = blk & 7;
  const int h    = (blk >> 3) & 255;
  const int b    = blk >> 11;
  const int tid  = threadIdx.x;
  const int lane = tid & 63;
  const int wv   = tid >> 6;         // wave id 0..3
  const int w0   = lane << 2;        // 4 pixels per lane

  __shared__ float lds_k[KS][Ww];    // 19456 B

  const int c0 = cg * 8 + wv * 2;    // this wave's 2 channels

  // ---- Phase 0: issue ALL x + skip loads into registers (14 x float4) ----
  const float* xb = x    + (size_t)b * NF * C * HW;
  const float* sb = skip + ((size_t)b * C + c0) * HW + (size_t)h * Ww + w0;

  float4 sv[2];
  float4 xv[2][6];                   // [ch][f*3 + ki]
#pragma unroll
  for (int ch = 0; ch < 2; ++ch) {
    sv[ch] = *(const float4*)(sb + (size_t)ch * HW);
#pragma unroll
    for (int f = 0; f < NF; ++f) {
#pragma unroll
      for (int ki = 0; ki < 3; ++ki) {
        const int hh = h + ki - 1;
        if (hh >= 0 && hh < Hh) {    // block-uniform
          const float* xr = xb + (size_t)(f * C + c0 + ch) * HW
                               + (size_t)hh * Ww + w0;
          xv[ch][f * 3 + ki] = *(const float4*)xr;
        } else {
          xv[ch][f * 3 + ki] = make_float4(0.f, 0.f, 0.f, 0.f);
        }
      }
    }
  }

  // ---- Phase 1: stage k rows to LDS (latency overlaps phase-0 loads) ----
  const float* kb = kk + (size_t)b * KS * HW + (size_t)h * Ww;
  for (int s = wv; s < KS; s += 4)
    *(float4*)&lds_k[s][w0] = *(const float4*)(kb + (size_t)s * HW + w0);
  __syncthreads();

  // ---- Phase 2: compute entirely from registers + LDS ----
  float4 k18 = *(const float4*)&lds_k[18][w0];
  float acc[2][4];
#pragma unroll
  for (int ch = 0; ch < 2; ++ch) {
    acc[ch][0] = k18.x * sv[ch].x; acc[ch][1] = k18.y * sv[ch].y;
    acc[ch][2] = k18.z * sv[ch].z; acc[ch][3] = k18.w * sv[ch].w;
  }

#pragma unroll
  for (int f = 0; f < NF; ++f) {
#pragma unroll
    for (int ki = 0; ki < 3; ++ki) {
      const int r = f * 3 + ki;
      float v[2][6];
#pragma unroll
      for (int ch = 0; ch < 2; ++ch) {
        v[ch][1] = xv[ch][r].x; v[ch][2] = xv[ch][r].y;
        v[ch][3] = xv[ch][r].z; v[ch][4] = xv[ch][r].w;
        float lf = __shfl_up(v[ch][4], 1);    // neighbor's w0-1
        float rg = __shfl_down(v[ch][1], 1);  // neighbor's w0+4
        v[ch][0] = (lane == 0)  ? 0.0f : lf;  // w == -1  -> pad
        v[ch][5] = (lane == 63) ? 0.0f : rg;  // w == 256 -> pad
      }
#pragma unroll
      for (int kj = 0; kj < 3; ++kj) {
        const int s = f * 9 + ki * 3 + kj;
        float4 kw = *(const float4*)&lds_k[s][w0];
#pragma unroll
        for (int ch = 0; ch < 2; ++ch) {
          acc[ch][0] = fmaf(kw.x, v[ch][0 + kj], acc[ch][0]);
          acc[ch][1] = fmaf(kw.y, v[ch][1 + kj], acc[ch][1]);
          acc[ch][2] = fmaf(kw.z, v[ch][2 + kj], acc[ch][2]);
          acc[ch][3] = fmaf(kw.w, v[ch][3 + kj], acc[ch][3]);
        }
      }
    }
  }

  float* ob = out + ((size_t)b * C + c0) * HW + (size_t)h * Ww + w0;
#pragma unroll
  for (int ch = 0; ch < 2; ++ch) {
    float4 o = make_float4(acc[ch][0], acc[ch][1], acc[ch][2], acc[ch][3]);
    *(float4*)(ob + (size_t)ch * HW) = o;
  }
}

extern "C" void kernel_launch(void* const* d_in, const int* in_sizes, int n_in,
                              void* d_out, int out_size, void* d_ws, size_t ws_size,
                              hipStream_t stream) {
  const float* kk = (const float*)d_in[0];   // [4, 19, 256, 256]
  const float* x  = (const float*)d_in[1];   // [4, 128, 256, 256]
  const float* sk = (const float*)d_in[2];   // [4, 64, 256, 256]
  float* out = (float*)d_out;                // [4, 64, 256, 256]

  dim3 grid(4 * Hh * 8);   // (b, h) rows x 8 channel groups
  dim3 block(256);
  filt_kernel<<<grid, block, 0, stream>>>(kk, x, sk, out);
}